// Round 13
// baseline (29.477 us; speedup 1.0000x reference)
//
#include <hip/hip_runtime.h>
#include <hip/hip_fp16.h>

#define NROWS 16384
#define NG 100
#define NC 10
#define NH 32
#define NS 10
#define GPC 10
#define SLOPE 0.2f
#define BN_EPS 1e-5f

#define RPB 32             // rows per block
#define BLOCK_A 1024       // 32 rows * 32 lanes/row; 16 waves = 1 block/CU (robust)
#define NB (NROWS / RPB)   // 512 blocks

// ---- DPP cross-lane adds (VALU pipe; verified rounds 7/8/11/12) ----
template<int CTRL>
__device__ __forceinline__ float dpp_add(float v) {
    int x = __builtin_bit_cast(int, v);
    int y = __builtin_amdgcn_update_dpp(0, x, CTRL, 0xF, 0xF, true);
    return v + __builtin_bit_cast(float, y);
}
__device__ __forceinline__ float row16_allreduce(float v) {
    v = dpp_add<0x128>(v);  // row_ror:8
    v = dpp_add<0x124>(v);  // row_ror:4
    v = dpp_add<0x122>(v);  // row_ror:2
    v = dpp_add<0x121>(v);  // row_ror:1
    return v;
}

// gather half-local chrom i (genes gl = i*10+gp, all compile-time):
// ONE ds_read_b64 per gene fetches {h:half2, e:f32}
#define GATHER(i, arr)                                                     \
    _Pragma("unroll")                                                      \
    for (int gp = 0; gp < GPC; ++gp) {                                     \
        const int gl_ = (i) * GPC + gp;                                    \
        const unsigned xg_ = (pk[gl_ >> 4] >> ((gl_ & 15) * 2)) & 3u;      \
        arr[gp] = cmbL[cbase + gl_ * 48 + ((int)xg_ << 4)];                \
    }

#define COMPUTE(arr, num, den) do {                                        \
    float e_[GPC];                                                         \
    _Pragma("unroll")                                                      \
    for (int gp = 0; gp < GPC; ++gp)                                       \
        e_[gp] = __builtin_bit_cast(float, arr[gp].y);                     \
    const float s01_ = (e_[0] + e_[1]) + (e_[2] + e_[3]);                  \
    const float s23_ = (e_[4] + e_[5]) + (e_[6] + e_[7]);                  \
    const float suma_ = (s01_ + s23_) + (e_[8] + e_[9]);                   \
    const float inv_ = 1.f / fmaxf(suma_, 1e-10f);                         \
    float2 chA_ = {0.f, 0.f}, chB_ = {0.f, 0.f};                           \
    _Pragma("unroll")                                                      \
    for (int gp = 0; gp < GPC; gp += 2) {                                  \
        float2 h0_ = __half22float2(__builtin_bit_cast(__half2, arr[gp].x)); \
        float2 h1_ = __half22float2(__builtin_bit_cast(__half2, arr[gp+1].x)); \
        chA_.x = fmaf(e_[gp],   h0_.x, chA_.x);                            \
        chA_.y = fmaf(e_[gp],   h0_.y, chA_.y);                            \
        chB_.x = fmaf(e_[gp+1], h1_.x, chB_.x);                            \
        chB_.y = fmaf(e_[gp+1], h1_.y, chB_.y);                            \
    }                                                                      \
    float2 ch_ = {chA_.x + chB_.x, chA_.y + chB_.y};                       \
    ch_.x = fmaxf(ch_.x, 0.f);  /* ReLU commutes with +ve 1/suma scale */  \
    ch_.y = fmaxf(ch_.y, 0.f);                                             \
    float pc_ = ch_.x * ca.x + ch_.y * ca.y;                               \
    pc_ = row16_allreduce(pc_);        /* full 32-h dot within 16 lanes */ \
    pc_ *= inv_;                       /* catt[n][c] */                    \
    const float lc_ = pc_ > 0.f ? pc_ : SLOPE * pc_;                       \
    const float ec_ = __expf(lc_);                                         \
    const float w_ = ec_ * inv_;                                           \
    num.x = fmaf(w_, ch_.x, num.x);                                        \
    num.y = fmaf(w_, ch_.y, num.y);                                        \
    den += ec_;                                                            \
} while (0)

// ================= main kernel =================
template<bool SLOTS>
__global__ __launch_bounds__(BLOCK_A, 4) void gga_main(
    const int* __restrict__ x, const float* __restrict__ emb,
    const float* __restrict__ gene_att, const float* __restrict__ chrom_att,
    const float* __restrict__ W, const float* __restrict__ b,
    float* __restrict__ y, float* __restrict__ P)
{
    __shared__ uint2 cmbL[300 * 16];   // 38.4 KB: {x = half2 h(2o,2o+1), y = f32 e}
    __shared__ float eL[300];
    __shared__ float WTL[NS * NH];     // WT[s][h]
    __shared__ float bL[NS];
    __shared__ unsigned xpL2[RPB * 2 * 4];  // per-row per-half repacked trits (1 KB)
    __shared__ float sAcc[2 * NS];

    const int t = threadIdx.x;
    const int n0 = blockIdx.x * RPB;

    // ---- phase 0 (round-8 ordering) ----
    if (t < 300) {                                     // e-table from global f32 emb
        const int g = t / 3;
        const float* ga = gene_att + (g / GPC) * NH;
        const float* e = emb + t * NH;
        float s = 0.f;
#pragma unroll
        for (int k = 0; k < NH; k += 4) {
            float4 ev = *reinterpret_cast<const float4*>(e + k);
            float4 gv = *reinterpret_cast<const float4*>(ga + k);
            s = fmaf(gv.x, ev.x, s); s = fmaf(gv.y, ev.y, s);
            s = fmaf(gv.z, ev.z, s); s = fmaf(gv.w, ev.w, s);
        }
        const float lk = s > 0.f ? s : SLOPE * s;
        eL[t] = (s != 0.f) ? __expf(lk) : 0.f;
    }
    if (t < NH * NS) WTL[t] = W[(t & 31) * NS + (t >> 5)];   // WT[s][h]
    if (t < NS) bL[t] = b[t];
    if (t < 2 * NS) sAcc[t] = 0.f;
    if (t < 256) {   // per-half trit repack: worker (row, half, word j)
        const int r = t >> 3, idx = t & 7;
        const int h = idx >> 2, j = idx & 3;
        const int gbase = 50 * h + 16 * j;             // even -> int2-aligned
        const int cnt = (j < 3) ? 16 : 2;              // word 3: trits 48,49 only
        const int2* p = reinterpret_cast<const int2*>(x + (n0 + r) * NG + gbase);
        unsigned pw = 0u;
#pragma unroll
        for (int k2 = 0; k2 < 8; ++k2) {
            if (k2 * 2 < cnt) {
                int2 v = p[k2];
                pw |= ((unsigned)v.x & 3u) << ((k2 * 2 + 0) * 2);
                pw |= ((unsigned)v.y & 3u) << ((k2 * 2 + 1) * 2);
            }
        }
        xpL2[(r * 2 + h) * 4 + j] = pw;
    }
    __syncthreads();

    // ---- phase 1: fused {h,e} table (coalesced float2 global reads) ----
#pragma unroll
    for (int i2 = 0; i2 < 5; ++i2) {
        const int i = t + i2 * BLOCK_A;
        if (i < 4800) {                                 // i = r3*16 + o
            float2 hv = reinterpret_cast<const float2*>(emb)[i];
            __half2 h2 = __floats2half2_rn(hv.x, hv.y);
            uint2 en;
            en.x = __builtin_bit_cast(unsigned, h2);
            en.y = __builtin_bit_cast(unsigned, eL[i >> 4]);
            cmbL[i] = en;
        }
    }
    __syncthreads();

    // ---- per-row: 32 lanes/row; half hf handles chroms 5hf..5hf+4 ----
    const int lr = t >> 5;          // row 0..31
    const int u = t & 31;
    const int o = u & 15;           // h-pair
    const int hf = u >> 4;          // chrom half
    const int n = n0 + lr;

    const float2 ca = reinterpret_cast<const float2*>(chrom_att)[o];

    const uint4 pk4 = *reinterpret_cast<const uint4*>(&xpL2[(lr * 2 + hf) * 4]);
    const unsigned pk[4] = {pk4.x, pk4.y, pk4.z, pk4.w};
    const int cbase = hf * 2400 + o;   // cmbL base: r3 = 150*hf + gl*3 + xg

    float2 num = {0.f, 0.f};
    float den = 0.f;

    // 2-deep pipeline over this half's 5 chroms
    uint2 hA[GPC], hB[GPC];
    GATHER(0, hA);
    {
        GATHER(1, hB); COMPUTE(hA, num, den);
        GATHER(2, hA); COMPUTE(hB, num, den);
        GATHER(3, hB); COMPUTE(hA, num, den);
        GATHER(4, hA); COMPUTE(hB, num, den);
        COMPUTE(hA, num, den);
    }

    // combine the two chrom-halves of this row (lanes u and u^16)
    den += __shfl_xor(den, 16);
    num.x += __shfl_xor(num.x, 16);
    num.y += __shfl_xor(num.y, 16);

    const float invd = 1.f / den;
    const float g0 = fmaxf(num.x * invd, 0.f);
    const float g1 = fmaxf(num.y * invd, 0.f);

    float ys[NS];
#pragma unroll
    for (int s = 0; s < NS; ++s) {
        const float2 wv = *reinterpret_cast<const float2*>(&WTL[s * NH + o * 2]);
        float p = g0 * wv.x + g1 * wv.y;
        p = row16_allreduce(p);          // each 16-group sums all 16 pairs
        ys[s] = p + bL[s];
    }

    if (u == 0) {
        float2* yp = reinterpret_cast<float2*>(y + n * NS);
#pragma unroll
        for (int s2 = 0; s2 < 5; ++s2) yp[s2] = make_float2(ys[2 * s2], ys[2 * s2 + 1]);
    }

    // BN partials: ys uniform across the 32 lanes of a row; wave = 2 rows.
    // bcast31 alone: lane63 = rowA + rowB (one dpp).
#pragma unroll
    for (int s = 0; s < NS; ++s) {
        float v  = dpp_add<0x143>(ys[s]);
        float v2 = dpp_add<0x143>(ys[s] * ys[s]);
        if ((t & 63) == 63) { atomicAdd(&sAcc[s], v); atomicAdd(&sAcc[NS + s], v2); }
    }
    __syncthreads();
    if (t < 2 * NS) {
        if (SLOTS) P[t * NB + blockIdx.x] = sAcc[t];   // plain store, no zeroing
        else       atomicAdd(&P[t], sAcc[t]);          // tiny-ws fallback
    }
}

// ------- BN finalize (round-8 proven config: 160 blocks x 256 threads) -------
template<bool SLOTS>
__global__ __launch_bounds__(256) void gga_bn(
    float* __restrict__ out, const float* __restrict__ P,
    const float* __restrict__ gamma, const float* __restrict__ beta)
{
    __shared__ float red[2 * NS * 8];
    __shared__ float scL[NS], shL[NS];
    const int t = threadIdx.x;

    if (SLOTS) {
        if (t < 2 * NS * 8) {                      // 160 reducer threads
            const int k = t >> 3, c = t & 7;
            const float4* p4 = reinterpret_cast<const float4*>(P + k * NB + c * 64);
            float s = 0.f;
#pragma unroll
            for (int i = 0; i < 16; ++i) {
                float4 v = p4[i];
                s += v.x + v.y + v.z + v.w;
            }
            red[t] = s;
        }
        __syncthreads();
    }
    if (t < NS) {
        float sm, sq;
        if (SLOTS) {
            sm = 0.f; sq = 0.f;
#pragma unroll
            for (int c = 0; c < 8; ++c) {
                sm += red[t * 8 + c];
                sq += red[(NS + t) * 8 + c];
            }
        } else {
            sm = P[t]; sq = P[NS + t];
        }
        const float mu = sm * (1.f / NROWS);
        float var = sq * (1.f / NROWS) - mu * mu;
        var = fmaxf(var, 0.f);
        const float r = rsqrtf(var + BN_EPS);
        scL[t] = gamma[t] * r;
        shL[t] = beta[t] - mu * scL[t];
    }
    __syncthreads();

    const int i4 = (blockIdx.x * 256 + t) * 4;
    float4 v = *reinterpret_cast<const float4*>(out + i4);
    const int s0 = i4 % NS;
    const int s1 = (s0 + 1) % NS, s2 = (s0 + 2) % NS, s3 = (s0 + 3) % NS;
    v.x = fmaf(v.x, scL[s0], shL[s0]);
    v.y = fmaf(v.y, scL[s1], shL[s1]);
    v.z = fmaf(v.z, scL[s2], shL[s2]);
    v.w = fmaf(v.w, scL[s3], shL[s3]);
    *reinterpret_cast<float4*>(out + i4) = v;
}

extern "C" void kernel_launch(void* const* d_in, const int* in_sizes, int n_in,
                              void* d_out, int out_size, void* d_ws, size_t ws_size,
                              hipStream_t stream) {
    const int*   x         = (const int*)d_in[0];
    const float* emb       = (const float*)d_in[1];
    const float* gene_att  = (const float*)d_in[2];
    const float* chrom_att = (const float*)d_in[3];
    const float* W         = (const float*)d_in[4];
    const float* b         = (const float*)d_in[5];
    const float* bn_gamma  = (const float*)d_in[6];
    const float* bn_beta   = (const float*)d_in[7];

    float* y = (float*)d_out;
    float* P = (float*)d_ws;   // SLOTS: P[2*NS][NB] = 40 KB, rewritten every launch

    if (ws_size >= (size_t)(2 * NS * NB * sizeof(float))) {
        gga_main<true><<<NB, BLOCK_A, 0, stream>>>(
            x, emb, gene_att, chrom_att, W, b, y, P);
        gga_bn<true><<<(NROWS * NS) / (256 * 4), 256, 0, stream>>>(
            y, P, bn_gamma, bn_beta);
    } else {
        hipMemsetAsync(P, 0, 2 * NS * sizeof(float), stream);
        gga_main<false><<<NB, BLOCK_A, 0, stream>>>(
            x, emb, gene_att, chrom_att, W, b, y, P);
        gga_bn<false><<<(NROWS * NS) / (256 * 4), 256, 0, stream>>>(
            y, P, bn_gamma, bn_beta);
    }
}